// Round 1
// baseline (876.969 us; speedup 1.0000x reference)
//
#include <hip/hip_runtime.h>
#include <math.h>

#define S_TOTAL 16384
#define N_NODES 512
#define N_PIPES 1024
#define N_DEM   256
#define HIDDEN  64

// ---------------- prep: MLP table net[p], pipe coefficient K[p] ----------------
__global__ void prep_net_K(const float* __restrict__ W1, const float* __restrict__ b1,
                           const float* __restrict__ W2, const float* __restrict__ b2,
                           const float* __restrict__ W3, const float* __restrict__ b3,
                           const float* __restrict__ base,
                           const float* __restrict__ L, const float* __restrict__ dpipe,
                           const float* __restrict__ C,
                           float* __restrict__ net, float* __restrict__ Kc) {
    int p = blockIdx.x * blockDim.x + threadIdx.x;
    if (p >= N_PIPES) return;
    float x = (float)p;
    float h1[HIDDEN];
    #pragma unroll
    for (int k = 0; k < HIDDEN; ++k) h1[k] = tanhf(x * W1[k] + b1[k]);
    float out = 0.f;
    for (int k = 0; k < HIDDEN; ++k) {
        float acc = b2[k];
        #pragma unroll
        for (int j = 0; j < HIDDEN; ++j) acc += h1[j] * W2[j * HIDDEN + k];
        out += tanhf(acc) * W3[k];
    }
    net[p] = base[p] + out + b3[0];
    Kc[p]  = 10.667f * powf(C[p], -1.852f) * powf(dpipe[p], -4.871f) * L[p];
}

// ---------------- prep: inverse demand map (node -> demand column or -1) -------
__global__ void prep_invmap(const int* __restrict__ demand_idx, int* __restrict__ invmap) {
    int t = threadIdx.x;
    if (t < N_NODES) invmap[t] = -1;
    __syncthreads();
    if (t < N_DEM) invmap[demand_idx[t]] = t;
}

// ---------------- G[i][p] = sum_n M[n][i] * inv[n][p]  (1024 x 1024) -----------
__global__ __launch_bounds__(256) void gemm_G(const float* __restrict__ M,
                                              const float* __restrict__ inv,
                                              float* __restrict__ G) {
    __shared__ float As[16][68];
    __shared__ float Bs[16][68];
    const int i0 = blockIdx.y * 64, p0 = blockIdx.x * 64;
    const int t = threadIdx.x, ty = t / 16, tx = t % 16;
    float acc[4][4] = {};
    for (int n0 = 0; n0 < N_NODES; n0 += 16) {
        const int k = t / 16, m4 = (t % 16) * 4;
        *(float4*)&As[k][m4] = *(const float4*)(M   + (size_t)(n0 + k) * N_PIPES + i0 + m4);
        *(float4*)&Bs[k][m4] = *(const float4*)(inv + (size_t)(n0 + k) * N_PIPES + p0 + m4);
        __syncthreads();
        #pragma unroll
        for (int k2 = 0; k2 < 16; ++k2) {
            float4 a4 = *(const float4*)&As[k2][ty * 4];
            float4 b4 = *(const float4*)&Bs[k2][tx * 4];
            float ar[4] = {a4.x, a4.y, a4.z, a4.w};
            float br[4] = {b4.x, b4.y, b4.z, b4.w};
            #pragma unroll
            for (int i = 0; i < 4; ++i)
                #pragma unroll
                for (int j = 0; j < 4; ++j) acc[i][j] += ar[i] * br[j];
        }
        __syncthreads();
    }
    #pragma unroll
    for (int i = 0; i < 4; ++i)
        #pragma unroll
        for (int j = 0; j < 4; ++j)
            G[(size_t)(i0 + ty * 4 + i) * N_PIPES + p0 + tx * 4 + j] = acc[i][j];
}

// ---------------- per-chunk: q and t = supply - hL(q) --------------------------
// q[s][p] = sum_j D[s][j]*inv[demand_idx[j]][p] + net[idx_s]*G[idx_s][p]
__global__ __launch_bounds__(256) void gemm_qt(const float* __restrict__ D,
                                               const int* __restrict__ leak_id,
                                               const float* __restrict__ inv,
                                               const int* __restrict__ demand_idx,
                                               const float* __restrict__ net,
                                               const float* __restrict__ G,
                                               const float* __restrict__ Kc,
                                               const float* __restrict__ supply,
                                               float* __restrict__ q,
                                               float* __restrict__ tb,
                                               int s_base) {
    __shared__ float As[16][68];   // As[k][m] = D[s0+m][j0+k]
    __shared__ float Bs[16][68];   // Bs[k][m] = inv[demand_idx[j0+k]][p0+m]
    const int sb = blockIdx.y * 64, p0 = blockIdx.x * 64;
    const int t = threadIdx.x, ty = t / 16, tx = t % 16;
    float acc[4][4] = {};
    for (int j0 = 0; j0 < N_DEM; j0 += 16) {
        {   // A load: float4 along j, transpose-scatter into LDS
            int m = t / 4, k4 = (t % 4) * 4;
            float4 v = *(const float4*)(D + (size_t)(s_base + sb + m) * N_DEM + j0 + k4);
            As[k4 + 0][m] = v.x; As[k4 + 1][m] = v.y; As[k4 + 2][m] = v.z; As[k4 + 3][m] = v.w;
            // B load: gathered rows of inv, contiguous in p
            int k = t / 16, m4 = (t % 16) * 4;
            int row = demand_idx[j0 + k];
            *(float4*)&Bs[k][m4] = *(const float4*)(inv + (size_t)row * N_PIPES + p0 + m4);
        }
        __syncthreads();
        #pragma unroll
        for (int k2 = 0; k2 < 16; ++k2) {
            float4 a4 = *(const float4*)&As[k2][ty * 4];
            float4 b4 = *(const float4*)&Bs[k2][tx * 4];
            float ar[4] = {a4.x, a4.y, a4.z, a4.w};
            float br[4] = {b4.x, b4.y, b4.z, b4.w};
            #pragma unroll
            for (int i = 0; i < 4; ++i)
                #pragma unroll
                for (int j = 0; j < 4; ++j) acc[i][j] += ar[i] * br[j];
        }
        __syncthreads();
    }
    #pragma unroll
    for (int i = 0; i < 4; ++i) {
        const int s  = sb + ty * 4 + i;       // within chunk
        const int gs = s_base + s;            // global sample
        const int idx = leak_id[gs];
        const float nv = net[idx];
        #pragma unroll
        for (int j = 0; j < 4; ++j) {
            const int p = p0 + tx * 4 + j;
            float qv = acc[i][j] + nv * G[(size_t)idx * N_PIPES + p];
            float hL = copysignf(Kc[p] * powf(fabsf(qv), 1.852f), qv);
            q [(size_t)s * N_PIPES + p] = qv;
            tb[(size_t)s * N_PIPES + p] = supply[p] - hL;
        }
    }
}

// ---------------- per-chunk: dual GEMM H=t*inv^T, r=q*A0^T, residual, reduce ---
__global__ __launch_bounds__(256) void gemm_res(const float* __restrict__ q,
                                                const float* __restrict__ tb,
                                                const float* __restrict__ inv,
                                                const float* __restrict__ A0,
                                                const float* __restrict__ M,
                                                const int* __restrict__ leak_id,
                                                const float* __restrict__ D,
                                                const int* __restrict__ invmap,
                                                const float* __restrict__ Cd_p,
                                                const float* __restrict__ a_p,
                                                int s_base, float scale,
                                                float* __restrict__ out) {
    __shared__ float Qs[16][68], Ts[16][68], Is[16][68], As0[16][68];
    const int sb = blockIdx.y * 64, n0 = blockIdx.x * 64;
    const int t = threadIdx.x, ty = t / 16, tx = t % 16;
    float accH[4][4] = {}, accR[4][4] = {};
    for (int p0 = 0; p0 < N_PIPES; p0 += 16) {
        const int m = t / 4, k4 = (t % 4) * 4;
        {
            float4 v = *(const float4*)(q  + (size_t)(sb + m) * N_PIPES + p0 + k4);
            Qs[k4 + 0][m] = v.x; Qs[k4 + 1][m] = v.y; Qs[k4 + 2][m] = v.z; Qs[k4 + 3][m] = v.w;
            float4 w = *(const float4*)(tb + (size_t)(sb + m) * N_PIPES + p0 + k4);
            Ts[k4 + 0][m] = w.x; Ts[k4 + 1][m] = w.y; Ts[k4 + 2][m] = w.z; Ts[k4 + 3][m] = w.w;
            float4 x = *(const float4*)(inv + (size_t)(n0 + m) * N_PIPES + p0 + k4);
            Is[k4 + 0][m] = x.x; Is[k4 + 1][m] = x.y; Is[k4 + 2][m] = x.z; Is[k4 + 3][m] = x.w;
            float4 y = *(const float4*)(A0 + (size_t)(n0 + m) * N_PIPES + p0 + k4);
            As0[k4 + 0][m] = y.x; As0[k4 + 1][m] = y.y; As0[k4 + 2][m] = y.z; As0[k4 + 3][m] = y.w;
        }
        __syncthreads();
        #pragma unroll
        for (int k2 = 0; k2 < 16; ++k2) {
            float4 qa = *(const float4*)&Qs[k2][ty * 4];
            float4 ta = *(const float4*)&Ts[k2][ty * 4];
            float4 ib = *(const float4*)&Is[k2][tx * 4];
            float4 ab = *(const float4*)&As0[k2][tx * 4];
            float qr[4] = {qa.x, qa.y, qa.z, qa.w};
            float tr[4] = {ta.x, ta.y, ta.z, ta.w};
            float ir[4] = {ib.x, ib.y, ib.z, ib.w};
            float ar[4] = {ab.x, ab.y, ab.z, ab.w};
            #pragma unroll
            for (int i = 0; i < 4; ++i)
                #pragma unroll
                for (int j = 0; j < 4; ++j) {
                    accH[i][j] += tr[i] * ir[j];
                    accR[i][j] += qr[i] * ar[j];
                }
        }
        __syncthreads();
    }
    const float sqrt2g = sqrtf(2.f * 9.80665f);
    const float cda = Cd_p[0] * a_p[0] * sqrt2g;
    float lsum = 0.f;
    #pragma unroll
    for (int i = 0; i < 4; ++i) {
        const int s  = sb + ty * 4 + i;
        const int gs = s_base + s;
        const int idx = leak_id[gs];
        #pragma unroll
        for (int j = 0; j < 4; ++j) {
            const int n = n0 + tx * 4 + j;
            const float H = accH[i][j];
            const float sq = (H > 0.f) ? sqrtf(H) : 0.f;
            const float dleak = cda * M[(size_t)n * N_PIPES + idx] * sq;
            const int jm = invmap[n];
            const float dem = (jm >= 0) ? D[(size_t)gs * N_DEM + jm] : 0.f;
            const float r = accR[i][j] - dem - dleak;
            lsum += r * r;
        }
    }
    // block reduction
    #pragma unroll
    for (int off = 32; off > 0; off >>= 1) lsum += __shfl_down(lsum, off, 64);
    __shared__ float wred[4];
    const int lane = t & 63, wid = t >> 6;
    if (lane == 0) wred[wid] = lsum;
    __syncthreads();
    if (t == 0) {
        float tot = wred[0] + wred[1] + wred[2] + wred[3];
        atomicAdd(out, tot * scale);
    }
}

extern "C" void kernel_launch(void* const* d_in, const int* in_sizes, int n_in,
                              void* d_out, int out_size, void* d_ws, size_t ws_size,
                              hipStream_t stream) {
    const float* D          = (const float*)d_in[0];
    const int*   leak_id    = (const int*)  d_in[1];
    const float* A0         = (const float*)d_in[2];
    const float* inv        = (const float*)d_in[3];
    const float* M          = (const float*)d_in[4];
    const float* supply     = (const float*)d_in[5];
    const float* L          = (const float*)d_in[6];
    const float* dpipe      = (const float*)d_in[7];
    const float* C          = (const float*)d_in[8];
    const float* a_p        = (const float*)d_in[9];
    const float* Cd_p       = (const float*)d_in[10];
    const float* W1         = (const float*)d_in[11];
    const float* b1         = (const float*)d_in[12];
    const float* W2         = (const float*)d_in[13];
    const float* b2         = (const float*)d_in[14];
    const float* W3         = (const float*)d_in[15];
    const float* b3         = (const float*)d_in[16];
    const float* base       = (const float*)d_in[17];
    const int*   demand_idx = (const int*)  d_in[18];

    // workspace carve (256B aligned)
    char* ws = (char*)d_ws;
    size_t off = 0;
    auto carve = [&](size_t bytes) { char* p = ws + off; off += (bytes + 255) & ~(size_t)255; return p; };
    float* G      = (float*)carve((size_t)N_PIPES * N_PIPES * 4);
    float* net    = (float*)carve(N_PIPES * 4);
    float* Kc     = (float*)carve(N_PIPES * 4);
    int*   invmap = (int*)  carve(N_NODES * 4);
    size_t fixed = off;

    int CS = 4096;
    while (CS > 64 && fixed + 2ull * CS * N_PIPES * 4 > ws_size) CS >>= 1;
    float* qbuf = (float*)carve((size_t)CS * N_PIPES * 4);
    float* tbuf = (float*)carve((size_t)CS * N_PIPES * 4);

    hipMemsetAsync(d_out, 0, (size_t)out_size * 4, stream);

    prep_net_K<<<4, 256, 0, stream>>>(W1, b1, W2, b2, W3, b3, base, L, dpipe, C, net, Kc);
    prep_invmap<<<1, 512, 0, stream>>>(demand_idx, invmap);
    gemm_G<<<dim3(16, 16), 256, 0, stream>>>(M, inv, G);

    const float scale = 1.f / ((float)S_TOTAL * (float)N_NODES);
    for (int s_base = 0; s_base < S_TOTAL; s_base += CS) {
        gemm_qt<<<dim3(N_PIPES / 64, CS / 64), 256, 0, stream>>>(
            D, leak_id, inv, demand_idx, net, G, Kc, supply, qbuf, tbuf, s_base);
        gemm_res<<<dim3(N_NODES / 64, CS / 64), 256, 0, stream>>>(
            qbuf, tbuf, inv, A0, M, leak_id, D, invmap, Cd_p, a_p,
            s_base, scale, (float*)d_out);
    }
}

// Round 3
// 267.594 us; speedup vs baseline: 3.2772x; 3.2772x over previous
//
#include <hip/hip_runtime.h>
#include <math.h>

typedef _Float16 f16;
typedef _Float16 f16x8 __attribute__((ext_vector_type(8)));
typedef float f32x4 __attribute__((ext_vector_type(4)));

#define S_TOTAL 16384
#define N_NODES 512
#define N_PIPES 1024
#define N_DEM   256
#define HIDDEN  64
#define T_SCALE 256.0f   // t = (supply - hL)/T_SCALE to fit f16 range; H *= T_SCALE

// ---------------- prep: MLP table net[p], pipe coefficient K[p] ----------------
__global__ void prep_net_K(const float* __restrict__ W1, const float* __restrict__ b1,
                           const float* __restrict__ W2, const float* __restrict__ b2,
                           const float* __restrict__ W3, const float* __restrict__ b3,
                           const float* __restrict__ base,
                           const float* __restrict__ L, const float* __restrict__ dpipe,
                           const float* __restrict__ C,
                           float* __restrict__ net, float* __restrict__ Kc) {
    int p = blockIdx.x * blockDim.x + threadIdx.x;
    if (p >= N_PIPES) return;
    float x = (float)p;
    float h1[HIDDEN];
    #pragma unroll
    for (int k = 0; k < HIDDEN; ++k) h1[k] = tanhf(x * W1[k] + b1[k]);
    float out = 0.f;
    for (int k = 0; k < HIDDEN; ++k) {
        float acc = b2[k];
        #pragma unroll
        for (int j = 0; j < HIDDEN; ++j) acc += h1[j] * W2[j * HIDDEN + k];
        out += tanhf(acc) * W3[k];
    }
    net[p] = base[p] + out + b3[0];
    Kc[p]  = 10.667f * powf(C[p], -1.852f) * powf(dpipe[p], -4.871f) * L[p];
}

// ---------------- prep: inverse demand map (node -> demand column or -1) -------
__global__ void prep_invmap(const int* __restrict__ demand_idx, int* __restrict__ invmap) {
    int t = threadIdx.x;
    if (t < N_NODES) invmap[t] = -1;
    __syncthreads();
    if (t < N_DEM) invmap[demand_idx[t]] = t;
}

// ---------------- f32 -> f16 conversion (grid-stride) --------------------------
__global__ void conv_to_f16(const float* __restrict__ in, f16* __restrict__ out, int n) {
    int i = blockIdx.x * blockDim.x + threadIdx.x;
    int stride = gridDim.x * blockDim.x;
    for (; i < n; i += stride) out[i] = (f16)in[i];
}

// ---------------- IDXT[p][j] = inv[demand_idx[j]][p]  (f16, 1024x256) ----------
__global__ void build_idxt(const float* __restrict__ inv, const int* __restrict__ demand_idx,
                           f16* __restrict__ idxt) {
    int p = blockIdx.x, j = threadIdx.x;
    idxt[(size_t)p * N_DEM + j] = (f16)inv[(size_t)demand_idx[j] * N_PIPES + p];
}

// ---------------- G[i][p] = sum_n M[n][i] * inv[n][p]  (f32, 1024x1024) --------
__global__ __launch_bounds__(256) void gemm_G(const float* __restrict__ M,
                                              const float* __restrict__ inv,
                                              float* __restrict__ G) {
    __shared__ float As[16][68];
    __shared__ float Bs[16][68];
    const int i0 = blockIdx.y * 64, p0 = blockIdx.x * 64;
    const int t = threadIdx.x, ty = t / 16, tx = t % 16;
    float acc[4][4] = {};
    for (int n0 = 0; n0 < N_NODES; n0 += 16) {
        const int k = t / 16, m4 = (t % 16) * 4;
        *(float4*)&As[k][m4] = *(const float4*)(M   + (size_t)(n0 + k) * N_PIPES + i0 + m4);
        *(float4*)&Bs[k][m4] = *(const float4*)(inv + (size_t)(n0 + k) * N_PIPES + p0 + m4);
        __syncthreads();
        #pragma unroll
        for (int k2 = 0; k2 < 16; ++k2) {
            float4 a4 = *(const float4*)&As[k2][ty * 4];
            float4 b4 = *(const float4*)&Bs[k2][tx * 4];
            float ar[4] = {a4.x, a4.y, a4.z, a4.w};
            float br[4] = {b4.x, b4.y, b4.z, b4.w};
            #pragma unroll
            for (int i = 0; i < 4; ++i)
                #pragma unroll
                for (int j = 0; j < 4; ++j) acc[i][j] += ar[i] * br[j];
        }
        __syncthreads();
    }
    #pragma unroll
    for (int i = 0; i < 4; ++i)
        #pragma unroll
        for (int j = 0; j < 4; ++j)
            G[(size_t)(i0 + ty * 4 + i) * N_PIPES + p0 + tx * 4 + j] = acc[i][j];
}

// ---------------- MFMA gemm_qt: q[s][p] = D*IDXT^T + nv*G[idx], t = supply-hL --
// tile: 128 s x 64 p, BK=64 over j. 4 waves (2x2), wave = 64s x 32p.
__global__ __launch_bounds__(256) void gemm_qt_mfma(
    const f16* __restrict__ D16, const int* __restrict__ leak_id,
    const f16* __restrict__ IDXT, const float* __restrict__ net,
    const float* __restrict__ G, const float* __restrict__ Kc,
    const float* __restrict__ supply,
    f16* __restrict__ q16, f16* __restrict__ t16, int s_base)
{
    __shared__ __align__(16) f16 Ad[128][72];
    __shared__ __align__(16) f16 Bi[64][72];
    const int nwg = gridDim.x * gridDim.y;
    const int bid = blockIdx.y * gridDim.x + blockIdx.x;
    const int w = (bid & 7) * (nwg >> 3) + (bid >> 3);   // XCD-contiguous work
    const int bx = w % gridDim.x, by = w / gridDim.x;
    const int p0 = bx * 64, sb = by * 128;
    const int t = threadIdx.x, lane = t & 63, wid = t >> 6;
    const int wr = wid >> 1, wc = wid & 1;
    const int cl = lane & 15, g = lane >> 4;
    const int tr = t >> 3, tc = (t & 7) * 8;

    f32x4 acc[4][2] = {};
    const f16* Dc = D16 + (size_t)(s_base + sb) * N_DEM;
    for (int j0 = 0; j0 < N_DEM; j0 += 64) {
        #pragma unroll
        for (int r = 0; r < 4; ++r) {
            int row = r * 32 + tr;
            *(f16x8*)&Ad[row][tc] = *(const f16x8*)(Dc + (size_t)row * N_DEM + j0 + tc);
        }
        #pragma unroll
        for (int r = 0; r < 2; ++r) {
            int row = r * 32 + tr;
            *(f16x8*)&Bi[row][tc] = *(const f16x8*)(IDXT + (size_t)(p0 + row) * N_DEM + j0 + tc);
        }
        __syncthreads();
        #pragma unroll
        for (int kk = 0; kk < 2; ++kk) {
            const int kb = kk * 32 + g * 8;
            f16x8 a[4], b[2];
            #pragma unroll
            for (int m = 0; m < 4; ++m) a[m] = *(const f16x8*)&Ad[wr * 64 + m * 16 + cl][kb];
            #pragma unroll
            for (int n = 0; n < 2; ++n) b[n] = *(const f16x8*)&Bi[wc * 32 + n * 16 + cl][kb];
            #pragma unroll
            for (int m = 0; m < 4; ++m)
                #pragma unroll
                for (int n = 0; n < 2; ++n)
                    acc[m][n] = __builtin_amdgcn_mfma_f32_16x16x32_f16(a[m], b[n], acc[m][n], 0, 0, 0);
        }
        __syncthreads();
    }
    float Kc2[2], sup2[2]; int pcol[2];
    #pragma unroll
    for (int n = 0; n < 2; ++n) {
        pcol[n] = p0 + wc * 32 + n * 16 + cl;
        Kc2[n] = Kc[pcol[n]]; sup2[n] = supply[pcol[n]];
    }
    #pragma unroll
    for (int m = 0; m < 4; ++m) {
        #pragma unroll
        for (int reg = 0; reg < 4; ++reg) {
            const int srow = wr * 64 + m * 16 + g * 4 + reg;
            const int gs = s_base + sb + srow;
            const int idx = leak_id[gs];
            const float nv = net[idx];
            #pragma unroll
            for (int n = 0; n < 2; ++n) {
                float qv = acc[m][n][reg] + nv * G[(size_t)idx * N_PIPES + pcol[n]];
                float hL = copysignf(Kc2[n] * powf(fabsf(qv), 1.852f), qv);
                size_t o = (size_t)(sb + srow) * N_PIPES + pcol[n];
                q16[o] = (f16)qv;
                t16[o] = (f16)((sup2[n] - hL) * (1.0f / T_SCALE));
            }
        }
    }
}

// ---------------- MFMA dual gemm_res: H = t*inv^T, r = q*A0^T, residual -------
// tile: 128 s x 64 n, BK=64 over p. 4 waves (2x2), wave = 64s x 32n.
__global__ __launch_bounds__(256) void gemm_res_mfma(
    const f16* __restrict__ q16, const f16* __restrict__ t16,
    const f16* __restrict__ inv16, const f16* __restrict__ A016,
    const float* __restrict__ M, const int* __restrict__ leak_id,
    const float* __restrict__ D, const int* __restrict__ invmap,
    const float* __restrict__ Cd_p, const float* __restrict__ a_p,
    int s_base, float scale, float* __restrict__ out)
{
    __shared__ __align__(16) f16 Aq[128][72], At[128][72], Bv[64][72], Ba[64][72];
    __shared__ float wred[4];
    const int nwg = gridDim.x * gridDim.y;
    const int bid = blockIdx.y * gridDim.x + blockIdx.x;
    const int w = (bid & 7) * (nwg >> 3) + (bid >> 3);
    const int bx = w % gridDim.x, by = w / gridDim.x;
    const int n0 = bx * 64, sb = by * 128;
    const int t = threadIdx.x, lane = t & 63, wid = t >> 6;
    const int wr = wid >> 1, wc = wid & 1;
    const int cl = lane & 15, g = lane >> 4;
    const int tr = t >> 3, tc = (t & 7) * 8;

    f32x4 accH[4][2] = {}, accR[4][2] = {};
    for (int p0 = 0; p0 < N_PIPES; p0 += 64) {
        #pragma unroll
        for (int r = 0; r < 4; ++r) {
            int row = r * 32 + tr;
            *(f16x8*)&Aq[row][tc] = *(const f16x8*)(q16 + (size_t)(sb + row) * N_PIPES + p0 + tc);
            *(f16x8*)&At[row][tc] = *(const f16x8*)(t16 + (size_t)(sb + row) * N_PIPES + p0 + tc);
        }
        #pragma unroll
        for (int r = 0; r < 2; ++r) {
            int row = r * 32 + tr;
            *(f16x8*)&Bv[row][tc] = *(const f16x8*)(inv16 + (size_t)(n0 + row) * N_PIPES + p0 + tc);
            *(f16x8*)&Ba[row][tc] = *(const f16x8*)(A016  + (size_t)(n0 + row) * N_PIPES + p0 + tc);
        }
        __syncthreads();
        #pragma unroll
        for (int kk = 0; kk < 2; ++kk) {
            const int kb = kk * 32 + g * 8;
            f16x8 aq[4], at[4], bv[2], ba[2];
            #pragma unroll
            for (int m = 0; m < 4; ++m) {
                aq[m] = *(const f16x8*)&Aq[wr * 64 + m * 16 + cl][kb];
                at[m] = *(const f16x8*)&At[wr * 64 + m * 16 + cl][kb];
            }
            #pragma unroll
            for (int n = 0; n < 2; ++n) {
                bv[n] = *(const f16x8*)&Bv[wc * 32 + n * 16 + cl][kb];
                ba[n] = *(const f16x8*)&Ba[wc * 32 + n * 16 + cl][kb];
            }
            #pragma unroll
            for (int m = 0; m < 4; ++m)
                #pragma unroll
                for (int n = 0; n < 2; ++n) {
                    accH[m][n] = __builtin_amdgcn_mfma_f32_16x16x32_f16(at[m], bv[n], accH[m][n], 0, 0, 0);
                    accR[m][n] = __builtin_amdgcn_mfma_f32_16x16x32_f16(aq[m], ba[n], accR[m][n], 0, 0, 0);
                }
        }
        __syncthreads();
    }
    const float cda = Cd_p[0] * a_p[0] * sqrtf(2.f * 9.80665f);
    int node[2], jm[2];
    #pragma unroll
    for (int n = 0; n < 2; ++n) {
        node[n] = n0 + wc * 32 + n * 16 + cl;
        jm[n] = invmap[node[n]];
    }
    float lsum = 0.f;
    #pragma unroll
    for (int m = 0; m < 4; ++m) {
        #pragma unroll
        for (int reg = 0; reg < 4; ++reg) {
            const int srow = wr * 64 + m * 16 + g * 4 + reg;
            const int gs = s_base + sb + srow;
            const int idx = leak_id[gs];
            #pragma unroll
            for (int n = 0; n < 2; ++n) {
                const float H = accH[m][n][reg] * T_SCALE;
                const float sq = (H > 0.f) ? sqrtf(H) : 0.f;
                const float dl = cda * M[(size_t)node[n] * N_PIPES + idx] * sq;
                const float dem = (jm[n] >= 0) ? D[(size_t)gs * N_DEM + jm[n]] : 0.f;
                const float r = accR[m][n][reg] - dem - dl;
                lsum += r * r;
            }
        }
    }
    #pragma unroll
    for (int off = 32; off > 0; off >>= 1) lsum += __shfl_down(lsum, off, 64);
    if (lane == 0) wred[wid] = lsum;
    __syncthreads();
    if (t == 0) atomicAdd(out, (wred[0] + wred[1] + wred[2] + wred[3]) * scale);
}

extern "C" void kernel_launch(void* const* d_in, const int* in_sizes, int n_in,
                              void* d_out, int out_size, void* d_ws, size_t ws_size,
                              hipStream_t stream) {
    const float* D          = (const float*)d_in[0];
    const int*   leak_id    = (const int*)  d_in[1];
    const float* A0         = (const float*)d_in[2];
    const float* inv        = (const float*)d_in[3];
    const float* M          = (const float*)d_in[4];
    const float* supply     = (const float*)d_in[5];
    const float* L          = (const float*)d_in[6];
    const float* dpipe      = (const float*)d_in[7];
    const float* C          = (const float*)d_in[8];
    const float* a_p        = (const float*)d_in[9];
    const float* Cd_p       = (const float*)d_in[10];
    const float* W1         = (const float*)d_in[11];
    const float* b1         = (const float*)d_in[12];
    const float* W2         = (const float*)d_in[13];
    const float* b2         = (const float*)d_in[14];
    const float* W3         = (const float*)d_in[15];
    const float* b3         = (const float*)d_in[16];
    const float* base       = (const float*)d_in[17];
    const int*   demand_idx = (const int*)  d_in[18];

    char* ws = (char*)d_ws;
    size_t off = 0;
    auto carve = [&](size_t bytes) { char* p = ws + off; off += (bytes + 255) & ~(size_t)255; return p; };
    float* G      = (float*)carve((size_t)N_PIPES * N_PIPES * 4);
    float* net    = (float*)carve(N_PIPES * 4);
    float* Kc     = (float*)carve(N_PIPES * 4);
    int*   invmap = (int*)  carve(N_NODES * 4);
    f16*   inv16  = (f16*)  carve((size_t)N_NODES * N_PIPES * 2);
    f16*   A016   = (f16*)  carve((size_t)N_NODES * N_PIPES * 2);
    f16*   IDXT   = (f16*)  carve((size_t)N_PIPES * N_DEM * 2);
    f16*   D16    = (f16*)  carve((size_t)S_TOTAL * N_DEM * 2);
    size_t fixed = off;

    int CS = S_TOTAL;
    while (CS > 512 && fixed + (size_t)CS * N_PIPES * 4 > ws_size) CS >>= 1;
    f16* q16 = (f16*)carve((size_t)CS * N_PIPES * 2);
    f16* t16 = (f16*)carve((size_t)CS * N_PIPES * 2);

    hipMemsetAsync(d_out, 0, (size_t)out_size * 4, stream);

    prep_net_K<<<4, 256, 0, stream>>>(W1, b1, W2, b2, W3, b3, base, L, dpipe, C, net, Kc);
    prep_invmap<<<1, 512, 0, stream>>>(demand_idx, invmap);
    conv_to_f16<<<512, 256, 0, stream>>>(inv, inv16, N_NODES * N_PIPES);
    conv_to_f16<<<512, 256, 0, stream>>>(A0, A016, N_NODES * N_PIPES);
    conv_to_f16<<<2048, 256, 0, stream>>>(D, D16, S_TOTAL * N_DEM);
    build_idxt<<<N_PIPES, N_DEM, 0, stream>>>(inv, demand_idx, IDXT);
    gemm_G<<<dim3(16, 16), 256, 0, stream>>>(M, inv, G);

    const float scale = 1.f / ((float)S_TOTAL * (float)N_NODES);
    for (int s_base = 0; s_base < S_TOTAL; s_base += CS) {
        gemm_qt_mfma<<<dim3(N_PIPES / 64, CS / 128), 256, 0, stream>>>(
            D16, leak_id, IDXT, net, G, Kc, supply, q16, t16, s_base);
        gemm_res_mfma<<<dim3(N_NODES / 64, CS / 128), 256, 0, stream>>>(
            q16, t16, inv16, A016, M, leak_id, D, invmap, Cd_p, a_p,
            s_base, scale, (float*)d_out);
    }
}